// Round 1
// baseline (608.733 us; speedup 1.0000x reference)
//
#include <hip/hip_runtime.h>

// Circular 3D cross-correlation via FFT (convolution theorem), B=8, V=128.
// out[b,t] = irfftn( rfftn(v1) * conj(rfftn(v2)) )
// Implemented as one packed complex FFT (Z = v1 + i*v2), Hermitian split,
// pointwise G = F1*conj(F2), inverse FFT, take real part.
//
// Forward per axis: radix-2 DIF (natural -> bit-reversed, in place).
// Inverse per axis: radix-2 DIT (bit-reversed -> natural, in place).
// Combine kernel undoes the per-axis bit-reversal when pairing k <-> -k.

#define V    128
#define V2   16384
#define V3   2097152
#define NB   8
#define PITCH 129   // +1 pad: column stride 129 floats -> conflict-free banks

__device__ __forceinline__ int bitrev7(int x) {
  return (int)(__brev((unsigned)x) >> 25);
}
// storage index of -k when storage is per-axis bit-reversed (involution)
__device__ __forceinline__ int negrev(int j) {
  int k = bitrev7(j);
  return bitrev7((V - k) & (V - 1));
}

// 128 lines x 128-pt FFT over an LDS tile.
// COLS=false: FFT along fast index (o = line*PITCH + i)   [x axis]
// COLS=true : FFT along slow index (o = i*PITCH + line)   [y or z axis]
// INV=false : forward DIF, twiddle e^{-2pi i j/(2h)}
// INV=true  : inverse DIT (unnormalized), twiddle e^{+2pi i j/(2h)}
template <bool COLS, bool INV>
__device__ __forceinline__ void fft128_stages(float* __restrict__ sre,
                                              float* __restrict__ sim,
                                              const float* __restrict__ twr,
                                              const float* __restrict__ twi,
                                              int tid, int nthr) {
  if (!INV) {
    for (int s = 6; s >= 0; --s) {
      const int h = 1 << s;
      for (int p = tid; p < 8192; p += nthr) {
        int q, line;
        if (COLS) { line = p & 127; q = p >> 7; }
        else      { q = p & 63;  line = p >> 6; }
        const int j  = q & (h - 1);
        const int g  = q >> s;
        const int i0 = (g << (s + 1)) + j;
        const int i1 = i0 + h;
        const int o0 = COLS ? (i0 * PITCH + line) : (line * PITCH + i0);
        const int o1 = COLS ? (i1 * PITCH + line) : (line * PITCH + i1);
        const int tw = j << (6 - s);
        const float wr = twr[tw], wi = twi[tw];
        const float ur = sre[o0], ui = sim[o0];
        const float vr = sre[o1], vi = sim[o1];
        sre[o0] = ur + vr;
        sim[o0] = ui + vi;
        const float dr = ur - vr, di = ui - vi;
        sre[o1] = dr * wr - di * wi;
        sim[o1] = dr * wi + di * wr;
      }
      __syncthreads();
    }
  } else {
    for (int s = 0; s <= 6; ++s) {
      const int h = 1 << s;
      for (int p = tid; p < 8192; p += nthr) {
        int q, line;
        if (COLS) { line = p & 127; q = p >> 7; }
        else      { q = p & 63;  line = p >> 6; }
        const int j  = q & (h - 1);
        const int g  = q >> s;
        const int i0 = (g << (s + 1)) + j;
        const int i1 = i0 + h;
        const int o0 = COLS ? (i0 * PITCH + line) : (line * PITCH + i0);
        const int o1 = COLS ? (i1 * PITCH + line) : (line * PITCH + i1);
        const int tw = j << (6 - s);
        const float wr = twr[tw], wi = -twi[tw];   // conj -> e^{+i...}
        const float vr = sre[o1], vi = sim[o1];
        const float tr = vr * wr - vi * wi;
        const float tt = vr * wi + vi * wr;
        const float ur = sre[o0], ui = sim[o0];
        sre[o0] = ur + tr;
        sim[o0] = ui + tt;
        sre[o1] = ur - tr;
        sim[o1] = ui - tt;
      }
      __syncthreads();
    }
  }
}

__device__ __forceinline__ void init_twiddles(float* twr, float* twi, int tid) {
  if (tid < 64) {
    const float a = -6.28318530717958647692f * (float)tid / 128.0f;
    twr[tid] = cosf(a);
    twi[tid] = sinf(a);
  }
}

// K1: pack Z = v1 + i*v2, forward FFT over x and y for one (b, z) plane.
__global__ __launch_bounds__(1024) void k_fwd_xy(const float* __restrict__ v1,
                                                 const float* __restrict__ v2,
                                                 float2* __restrict__ Z) {
  __shared__ float sre[V * PITCH];
  __shared__ float sim[V * PITCH];
  __shared__ float twr[64], twi[64];
  const int tid = threadIdx.x;
  const int b   = blockIdx.x >> 7;
  const int zc  = blockIdx.x & 127;
  init_twiddles(twr, twi, tid);
  const size_t base = (size_t)b * V3 + (size_t)zc * V2;
  for (int p = tid; p < V2; p += 1024) {
    const int y = p >> 7, x = p & 127;
    sre[y * PITCH + x] = v1[base + p];
    sim[y * PITCH + x] = v2[base + p];
  }
  __syncthreads();
  fft128_stages<false, false>(sre, sim, twr, twi, tid, 1024);  // x
  fft128_stages<true,  false>(sre, sim, twr, twi, tid, 1024);  // y
  for (int p = tid; p < V2; p += 1024) {
    const int y = p >> 7, x = p & 127;
    Z[base + p] = make_float2(sre[y * PITCH + x], sim[y * PITCH + x]);
  }
}

// K2/K4: FFT along z for one (b, y) tile of lines, in place.
template <bool INV>
__global__ __launch_bounds__(1024) void k_z(float2* __restrict__ Z) {
  __shared__ float sre[V * PITCH];
  __shared__ float sim[V * PITCH];
  __shared__ float twr[64], twi[64];
  const int tid = threadIdx.x;
  const int b   = blockIdx.x >> 7;
  const int y   = blockIdx.x & 127;
  init_twiddles(twr, twi, tid);
  const size_t base = (size_t)b * V3 + (size_t)y * V;
  for (int p = tid; p < V2; p += 1024) {
    const int z = p >> 7, x = p & 127;
    const float2 v = Z[base + (size_t)z * V2 + x];
    sre[z * PITCH + x] = v.x;
    sim[z * PITCH + x] = v.y;
  }
  __syncthreads();
  fft128_stages<true, INV>(sre, sim, twr, twi, tid, 1024);     // z (slow idx)
  for (int p = tid; p < V2; p += 1024) {
    const int z = p >> 7, x = p & 127;
    Z[base + (size_t)z * V2 + x] =
        make_float2(sre[z * PITCH + x], sim[z * PITCH + x]);
  }
}

// K3: G(k) = F1(k) * conj(F2(k)) from packed spectrum, in place, paired k/-k.
__global__ __launch_bounds__(256) void k_combine(float2* __restrict__ Z) {
  const int t   = blockIdx.x * 256 + threadIdx.x;
  const int b   = t >> 21;
  const int idx = t & (V3 - 1);
  const int jx = idx & 127, jy = (idx >> 7) & 127, jz = idx >> 14;
  const int jxm = negrev(jx), jym = negrev(jy), jzm = negrev(jz);
  const int idxm = (jzm << 14) | (jym << 7) | jxm;
  if (idxm < idx) return;  // each unordered pair handled once
  const size_t p0 = (size_t)b * V3 + (size_t)idx;
  const size_t p1 = (size_t)b * V3 + (size_t)idxm;
  const float2 A  = Z[p0];
  const float2 Bv = Z[p1];
  // F1 = (A + conj(B))/2 ; F2 = (A - conj(B))/(2i)
  const float f1r = 0.5f * (A.x + Bv.x);
  const float f1i = 0.5f * (A.y - Bv.y);
  const float f2r = 0.5f * (A.y + Bv.y);
  const float f2i = 0.5f * (Bv.x - A.x);
  // G = F1 * conj(F2)
  const float gr = f1r * f2r + f1i * f2i;
  const float gi = f1i * f2r - f1r * f2i;
  Z[p0] = make_float2(gr, gi);
  if (idxm != idx) Z[p1] = make_float2(gr, -gi);  // G(-k) = conj(G(k))
}

// K5: inverse FFT over x and y for one (b, z) plane, write real out * 1/V^3.
__global__ __launch_bounds__(1024) void k_inv_xy(const float2* __restrict__ Z,
                                                 float* __restrict__ out) {
  __shared__ float sre[V * PITCH];
  __shared__ float sim[V * PITCH];
  __shared__ float twr[64], twi[64];
  const int tid = threadIdx.x;
  const int b   = blockIdx.x >> 7;
  const int zc  = blockIdx.x & 127;
  init_twiddles(twr, twi, tid);
  const size_t base = (size_t)b * V3 + (size_t)zc * V2;
  for (int p = tid; p < V2; p += 1024) {
    const int y = p >> 7, x = p & 127;
    const float2 v = Z[base + p];
    sre[y * PITCH + x] = v.x;
    sim[y * PITCH + x] = v.y;
  }
  __syncthreads();
  fft128_stages<false, true>(sre, sim, twr, twi, tid, 1024);   // x
  fft128_stages<true,  true>(sre, sim, twr, twi, tid, 1024);   // y
  const float scale = 1.0f / 2097152.0f;  // 1/V^3
  for (int p = tid; p < V2; p += 1024) {
    const int y = p >> 7, x = p & 127;
    out[base + p] = sre[y * PITCH + x] * scale;
  }
}

extern "C" void kernel_launch(void* const* d_in, const int* in_sizes, int n_in,
                              void* d_out, int out_size, void* d_ws, size_t ws_size,
                              hipStream_t stream) {
  const float* v1 = (const float*)d_in[0];
  const float* v2 = (const float*)d_in[1];
  float* out = (float*)d_out;
  float2* Z  = (float2*)d_ws;  // needs NB*V3*8 = 128 MiB

  k_fwd_xy<<<NB * V, 1024, 0, stream>>>(v1, v2, Z);
  k_z<false><<<NB * V, 1024, 0, stream>>>(Z);
  k_combine<<<(NB * V3) / 256, 256, 0, stream>>>(Z);
  k_z<true><<<NB * V, 1024, 0, stream>>>(Z);
  k_inv_xy<<<NB * V, 1024, 0, stream>>>(Z, out);
}

// Round 2
// 504.458 us; speedup vs baseline: 1.2067x; 1.2067x over previous
//
#include <hip/hip_runtime.h>
#include <math.h>

// Circular 3D cross-correlation via FFT, B=8, V=128.
// Z = v1 + i*v2 packed complex FFT; Hermitian split; G = F1*conj(F2); inverse.
// Storage convention: each transformed axis is held in bit-reversed order
// (DIF forward: natural->bitrev; DIT inverse: bitrev->natural). The combine
// maps storage->frequency with bitrev7 per axis (identical to round-1 math).
//
// Round-2 mechanics: wave-per-line shuffle FFT (2 complex/lane, butterflies
// via __shfl_xor, per-lane stage twiddles precomputed in registers), and the
// z-fwd + combine + z-inv passes fused into one kernel operating on y-pair
// half-tiles resident in LDS. 3 kernels, ~704 MiB HBM traffic total.

#define V    128
#define V2   16384
#define V3   2097152
#define NB   8
#define PF   129   // LDS pitch (float2) for full 128-wide plane
#define PH   65    // LDS pitch (float2) for 64-wide half tiles

__device__ __forceinline__ int bitrev7(int x) {
  return (int)(__brev((unsigned)x) >> 25);
}
// storage index of -k when storage is per-axis bit-reversed (involution)
__device__ __forceinline__ int negrev(int j) {
  int k = bitrev7(j);
  return bitrev7((V - k) & (V - 1));
}

__device__ __forceinline__ float2 shflx(float2 v, int mask) {
  float2 r;
  r.x = __shfl_xor(v.x, mask, 64);
  r.y = __shfl_xor(v.y, mask, 64);
  return r;
}

// Wave-wide 128-pt radix-2 FFT. Lane l holds a[l] (c0) and a[l+64] (c1).
// Fwd: in-place DIF, natural in -> bitrev out. Inv: DIT, bitrev in -> natural
// out, unnormalized. Twiddles are per-lane constants computed once in init().
template <bool INV>
struct WaveFFT {
  float2 t64;     // W128^l (conj for INV) — h=64 within-lane stage
  float2 ts[6];   // stage s (h=1<<s): fwd: upper? W128^e : (1,0); inv: W128^-e
  float  sg[6];   // upper ? -1 : +1
  int    lane;

  __device__ void init(int l) {
    lane = l;
    const float k = -6.28318530717958647692f / 128.0f;
    t64.x = cosf(k * (float)l);
    t64.y = sinf(k * (float)l);
    if (INV) t64.y = -t64.y;
#pragma unroll
    for (int s = 0; s < 6; ++s) {
      const int h = 1 << s;
      const int e = (l & (h - 1)) << (6 - s);
      float cr = cosf(k * (float)e);
      float ci = sinf(k * (float)e);
      if (INV) ci = -ci;
      const bool up = (l >> s) & 1;
      sg[s] = up ? -1.0f : 1.0f;
      if (!INV) {
        ts[s] = up ? make_float2(cr, ci) : make_float2(1.0f, 0.0f);
      } else {
        ts[s] = make_float2(cr, ci);
      }
    }
  }

  __device__ __forceinline__ float2 bf_fwd(float2 c, int h, int s) {
    // lower: a[j]+a[j+h]; upper: (a[j]-a[j+h])*W  — uniform via sg/identity-W
    float2 p = shflx(c, h);
    float2 t;
    t.x = fmaf(c.x, sg[s], p.x);
    t.y = fmaf(c.y, sg[s], p.y);
    float2 r;
    r.x = t.x * ts[s].x - t.y * ts[s].y;
    r.y = t.x * ts[s].y + t.y * ts[s].x;
    return r;
  }

  __device__ __forceinline__ float2 bf_inv(float2 c, int h, int s) {
    // t = a[j+h]*conjW; lower: a[j]+t; upper: a[j]-t
    float2 p = shflx(c, h);
    const bool up = (lane >> s) & 1;
    float2 src = up ? c : p;     // the a[j+h] value
    float2 m;
    m.x = src.x * ts[s].x - src.y * ts[s].y;
    m.y = src.x * ts[s].y + src.y * ts[s].x;
    float2 base = up ? p : c;    // the a[j] value
    float2 r;
    r.x = fmaf(m.x, sg[s], base.x);
    r.y = fmaf(m.y, sg[s], base.y);
    return r;
  }

  __device__ void run(float2& c0, float2& c1) {
    if (!INV) {
      // h = 64 (within lane)
      float dx = c0.x - c1.x, dy = c0.y - c1.y;
      float2 u = make_float2(c0.x + c1.x, c0.y + c1.y);
      float2 v;
      v.x = dx * t64.x - dy * t64.y;
      v.y = dx * t64.y + dy * t64.x;
      c0 = u; c1 = v;
#pragma unroll
      for (int s = 5; s >= 0; --s) {
        c0 = bf_fwd(c0, 1 << s, s);
        c1 = bf_fwd(c1, 1 << s, s);
      }
    } else {
#pragma unroll
      for (int s = 0; s <= 5; ++s) {
        c0 = bf_inv(c0, 1 << s, s);
        c1 = bf_inv(c1, 1 << s, s);
      }
      // h = 64 (within lane)
      float2 t;
      t.x = c1.x * t64.x - c1.y * t64.y;
      t.y = c1.x * t64.y + c1.y * t64.x;
      float2 u = make_float2(c0.x + t.x, c0.y + t.y);
      float2 w = make_float2(c0.x - t.x, c0.y - t.y);
      c0 = u; c1 = w;
    }
  }
};

// K1: pack Z = v1 + i*v2; forward y-FFT (columns) then x-FFT (rows) of one
// (b,z) plane; write Z coalesced.
__global__ __launch_bounds__(1024) void k_fwd_xy(const float* __restrict__ v1,
                                                 const float* __restrict__ v2,
                                                 float2* __restrict__ Z) {
  __shared__ float2 s[V * PF];
  const int tid = threadIdx.x, lane = tid & 63, wave = tid >> 6;
  const int b = blockIdx.x >> 7, zc = blockIdx.x & 127;
  const size_t base = (size_t)b * V3 + (size_t)zc * V2;
  WaveFFT<false> F;
  F.init(lane);
  for (int p = tid; p < V2; p += 1024) {
    const int y = p >> 7, x = p & 127;
    s[y * PF + x] = make_float2(v1[base + p], v2[base + p]);
  }
  __syncthreads();
  for (int c = wave; c < 128; c += 16) {       // y-FFT down columns
    float2 c0 = s[lane * PF + c];
    float2 c1 = s[(lane + 64) * PF + c];
    F.run(c0, c1);
    s[lane * PF + c] = c0;
    s[(lane + 64) * PF + c] = c1;
  }
  __syncthreads();
  for (int y = wave; y < 128; y += 16) {       // x-FFT along rows, store
    float2 c0 = s[y * PF + lane];
    float2 c1 = s[y * PF + lane + 64];
    F.run(c0, c1);
    Z[base + y * 128 + lane]      = c0;
    Z[base + y * 128 + lane + 64] = c1;
  }
}

// K2: fused forward z-FFT + combine + inverse z-FFT on a y-pair (yA, yB =
// negrev(yA)) for one x-half. Two 128(z) x 64(x) tiles in LDS.
__global__ __launch_bounds__(1024) void k_z_fused(float2* __restrict__ Z) {
  __shared__ float2 A[V * PH];
  __shared__ float2 Bt[V * PH];
  const int tid = threadIdx.x, lane = tid & 63, wave = tid >> 6;
  const int blk = blockIdx.x;
  const int b  = blk / 130;
  const int r  = blk % 130;
  const int g  = r >> 1;
  const int xh = r & 1;
  int yA, yB;
  if (g < 2) {               // self-paired storage rows: negrev(0)=0, negrev(1)=1
    yA = yB = g;
  } else {
    int cnt = g - 2, j = 0;
    for (j = 0; j < 128; ++j) {
      if (j < negrev(j)) {
        if (cnt == 0) break;
        --cnt;
      }
    }
    yA = j;
    yB = negrev(j);
  }
  const bool self = (yA == yB);
  const size_t baseA = (size_t)b * V3 + (size_t)yA * V + (size_t)xh * 64;
  const size_t baseB = (size_t)b * V3 + (size_t)yB * V + (size_t)xh * 64;
  WaveFFT<false> Ff;  Ff.init(lane);
  WaveFFT<true>  Fi;  Fi.init(lane);

  for (int p = tid; p < 8192; p += 1024) {
    const int z = p >> 6, x = p & 63;
    A[z * PH + x] = Z[baseA + (size_t)z * V2 + x];
  }
  if (!self) {
    for (int p = tid; p < 8192; p += 1024) {
      const int z = p >> 6, x = p & 63;
      Bt[z * PH + x] = Z[baseB + (size_t)z * V2 + x];
    }
  }
  __syncthreads();

  const int ncol = self ? 64 : 128;
  for (int c = wave; c < ncol; c += 16) {      // forward z-FFT down columns
    float2* T = (c < 64) ? A : Bt;
    const int cc = c & 63;
    float2 c0 = T[lane * PH + cc];
    float2 c1 = T[(lane + 64) * PH + cc];
    Ff.run(c0, c1);
    T[lane * PH + cc] = c0;
    T[(lane + 64) * PH + cc] = c1;
  }
  __syncthreads();

  // combine: G = F1*conj(F2); A[z,x] pairs with B[negrev z, negrev x]
  if (!self) {
    for (int p = tid; p < 8192; p += 1024) {
      const int z = p >> 6, x = p & 63;
      const int zm = negrev(z);
      const int xm = negrev(xh * 64 + x) & 63;  // x-half closed under negrev
      const float2 a  = A[z * PH + x];
      const float2 bb = Bt[zm * PH + xm];
      const float f1r = 0.5f * (a.x + bb.x);
      const float f1i = 0.5f * (a.y - bb.y);
      const float f2r = 0.5f * (a.y + bb.y);
      const float f2i = 0.5f * (bb.x - a.x);
      const float gr = f1r * f2r + f1i * f2i;
      const float gi = f1i * f2r - f1r * f2i;
      A[z * PH + x]    = make_float2(gr, gi);
      Bt[zm * PH + xm] = make_float2(gr, -gi);
    }
  } else {
    for (int p = tid; p < 8192; p += 1024) {
      const int z = p >> 6, x = p & 63;
      const int zm = negrev(z);
      const int xm = negrev(xh * 64 + x) & 63;
      const int pm = zm * 64 + xm;
      if (pm < p) continue;                     // each unordered pair once
      const float2 a  = A[z * PH + x];
      const float2 bb = A[zm * PH + xm];
      const float f1r = 0.5f * (a.x + bb.x);
      const float f1i = 0.5f * (a.y - bb.y);
      const float f2r = 0.5f * (a.y + bb.y);
      const float f2i = 0.5f * (bb.x - a.x);
      const float gr = f1r * f2r + f1i * f2i;
      const float gi = f1i * f2r - f1r * f2i;
      A[z * PH + x] = make_float2(gr, gi);
      if (pm != p) A[zm * PH + xm] = make_float2(gr, -gi);
    }
  }
  __syncthreads();

  for (int c = wave; c < ncol; c += 16) {      // inverse z-FFT down columns
    float2* T = (c < 64) ? A : Bt;
    const int cc = c & 63;
    float2 c0 = T[lane * PH + cc];
    float2 c1 = T[(lane + 64) * PH + cc];
    Fi.run(c0, c1);
    T[lane * PH + cc] = c0;
    T[(lane + 64) * PH + cc] = c1;
  }
  __syncthreads();

  for (int p = tid; p < 8192; p += 1024) {
    const int z = p >> 6, x = p & 63;
    Z[baseA + (size_t)z * V2 + x] = A[z * PH + x];
  }
  if (!self) {
    for (int p = tid; p < 8192; p += 1024) {
      const int z = p >> 6, x = p & 63;
      Z[baseB + (size_t)z * V2 + x] = Bt[z * PH + x];
    }
  }
}

// K3: inverse y-FFT (columns) then x-FFT (rows) of one (b,z) plane; write
// real part * 1/V^3.
__global__ __launch_bounds__(1024) void k_inv_xy(const float2* __restrict__ Z,
                                                 float* __restrict__ out) {
  __shared__ float2 s[V * PF];
  const int tid = threadIdx.x, lane = tid & 63, wave = tid >> 6;
  const int b = blockIdx.x >> 7, zc = blockIdx.x & 127;
  const size_t base = (size_t)b * V3 + (size_t)zc * V2;
  WaveFFT<true> F;
  F.init(lane);
  for (int p = tid; p < V2; p += 1024) {
    const int y = p >> 7, x = p & 127;
    s[y * PF + x] = Z[base + p];
  }
  __syncthreads();
  for (int c = wave; c < 128; c += 16) {       // inverse y-FFT down columns
    float2 c0 = s[lane * PF + c];
    float2 c1 = s[(lane + 64) * PF + c];
    F.run(c0, c1);
    s[lane * PF + c] = c0;
    s[(lane + 64) * PF + c] = c1;
  }
  __syncthreads();
  const float sc = 1.0f / 2097152.0f;          // 1/V^3
  for (int y = wave; y < 128; y += 16) {       // inverse x-FFT, real store
    float2 c0 = s[y * PF + lane];
    float2 c1 = s[y * PF + lane + 64];
    F.run(c0, c1);
    out[base + y * 128 + lane]      = c0.x * sc;
    out[base + y * 128 + lane + 64] = c1.x * sc;
  }
}

extern "C" void kernel_launch(void* const* d_in, const int* in_sizes, int n_in,
                              void* d_out, int out_size, void* d_ws, size_t ws_size,
                              hipStream_t stream) {
  const float* v1 = (const float*)d_in[0];
  const float* v2 = (const float*)d_in[1];
  float* out = (float*)d_out;
  float2* Z  = (float2*)d_ws;  // NB*V3*8 = 128 MiB

  k_fwd_xy<<<NB * V, 1024, 0, stream>>>(v1, v2, Z);
  k_z_fused<<<NB * 130, 1024, 0, stream>>>(Z);   // 8 b x 65 y-groups x 2 x-halves
  k_inv_xy<<<NB * V, 1024, 0, stream>>>(Z, out);
}

// Round 3
// 420.179 us; speedup vs baseline: 1.4487x; 1.2006x over previous
//
#include <hip/hip_runtime.h>
#include <math.h>

// Circular 3D cross-correlation via FFT, B=8, V=128.
// Z = v1 + i*v2 packed complex FFT; Hermitian split; G = F1*conj(F2); inverse.
// Storage: each transformed axis held in bit-reversed order (DIF fwd:
// natural->bitrev; DIT inv: bitrev->natural); combine pairs k<->-k via
// bitrev7 per axis (same convention as rounds 1-2, which passed).
//
// Round-3 mechanics:
//  * 4 complex per lane, 32 lanes per line, 2 lines per wave. Stages h=64 and
//    h=32 are within-lane (radix-4 head, no shuffles); 5 cross-lane stages
//    with xor masks <=16 (cheap ds_swizzle). 8 independent chains per wave.
//  * Z stored transposed as (b, x, z, y): K1 writes y-FFT results straight to
//    global (y-contiguous), K3 reads them likewise -> K1/K3 need only 2 LDS
//    passes + 1 barrier each. K2 blocks on x-pairs; its (z,y) tiles are fully
//    contiguous in global memory.

#define V    128
#define V2   16384
#define V3   2097152
#define NB   8
#define PF   129          // LDS pitch (float2) for 128x128 plane
#define PH   65           // LDS pitch (float2) for 128x64 half tiles
#define TILE (V * PH)

__device__ __forceinline__ int bitrev7(int x) {
  return (int)(__brev((unsigned)x) >> 25);
}
__device__ __forceinline__ int negrev(int j) {
  int k = bitrev7(j);
  return bitrev7((V - k) & (V - 1));
}

__device__ __forceinline__ float2 cmul(float2 a, float2 b) {
  return make_float2(a.x * b.x - a.y * b.y, a.x * b.y + a.y * b.x);
}
__device__ __forceinline__ float2 f2add(float2 a, float2 b) {
  return make_float2(a.x + b.x, a.y + b.y);
}
__device__ __forceinline__ float2 f2sub(float2 a, float2 b) {
  return make_float2(a.x - b.x, a.y - b.y);
}
__device__ __forceinline__ float2 shflx(float2 v, int m) {
  return make_float2(__shfl_xor(v.x, m, 64), __shfl_xor(v.y, m, 64));
}

// 128-pt radix-2 FFT distributed as: lane ll (0..31 within half-wave) holds
// elements {ll, ll+32, ll+64, ll+96}. Fwd DIF: h=64,32 within-lane, then 5
// cross-lane stages (h=16..1). Inv DIT mirrored. Twiddles per-lane constants.
template <bool INV>
struct WF4 {
  float2 wA, wB, w32;  // h=64 twiddles (q=0,1) and h=32 twiddle
  float2 ts[5];        // cross stage sbit: fwd: up?W128^e:(1,0); inv: conj
  float  sg[5];
  int    ll;

  __device__ void init(int lane) {
    ll = lane & 31;
    const float k = -6.28318530717958647692f / 128.0f;
    const float ca = cosf(k * (float)ll), sa = sinf(k * (float)ll);
    const float c2 = cosf(k * (float)(2 * ll)), s2 = sinf(k * (float)(2 * ll));
    if (!INV) {
      wA = make_float2(ca, sa);          // W128^ll
      wB = make_float2(sa, -ca);         // W128^ll * (-i)
      w32 = make_float2(c2, s2);         // W64^ll
    } else {
      wA = make_float2(ca, -sa);         // conj(W128^ll)
      wB = make_float2(sa, ca);          // conj(W128^ll) * i
      w32 = make_float2(c2, -s2);        // conj(W64^ll)
    }
#pragma unroll
    for (int sb = 0; sb < 5; ++sb) {
      const int h = 1 << sb;
      const int e = (ll & (h - 1)) * (64 >> sb);  // (ll%h)*(64/h)
      const float ce = cosf(k * (float)e), se = sinf(k * (float)e);
      const bool up = (ll >> sb) & 1;
      sg[sb] = up ? -1.0f : 1.0f;
      if (!INV) ts[sb] = up ? make_float2(ce, se) : make_float2(1.0f, 0.0f);
      else      ts[sb] = make_float2(ce, -se);
    }
  }

  __device__ __forceinline__ float2 bff(float2 c, int sb) {
    float2 p = shflx(c, 1 << sb);
    float2 t = make_float2(fmaf(c.x, sg[sb], p.x), fmaf(c.y, sg[sb], p.y));
    return cmul(t, ts[sb]);
  }
  __device__ __forceinline__ float2 bfi(float2 c, int sb) {
    float2 p = shflx(c, 1 << sb);
    const bool up = (ll >> sb) & 1;
    float2 src = up ? c : p;
    float2 m = cmul(src, ts[sb]);
    float2 base = up ? p : c;
    return make_float2(fmaf(m.x, sg[sb], base.x), fmaf(m.y, sg[sb], base.y));
  }

  __device__ void run(float2& c0, float2& c1, float2& c2, float2& c3) {
    if (!INV) {
      float2 d0 = f2sub(c0, c2), d1 = f2sub(c1, c3);
      c0 = f2add(c0, c2); c1 = f2add(c1, c3);
      c2 = cmul(d0, wA);  c3 = cmul(d1, wB);
      float2 e0 = f2sub(c0, c1), e1 = f2sub(c2, c3);
      c0 = f2add(c0, c1); c1 = cmul(e0, w32);
      c2 = f2add(c2, c3); c3 = cmul(e1, w32);
#pragma unroll
      for (int sb = 4; sb >= 0; --sb) {
        c0 = bff(c0, sb); c1 = bff(c1, sb); c2 = bff(c2, sb); c3 = bff(c3, sb);
      }
    } else {
#pragma unroll
      for (int sb = 0; sb < 5; ++sb) {
        c0 = bfi(c0, sb); c1 = bfi(c1, sb); c2 = bfi(c2, sb); c3 = bfi(c3, sb);
      }
      float2 t, n;
      t = cmul(c1, w32); n = f2add(c0, t); c1 = f2sub(c0, t); c0 = n;
      t = cmul(c3, w32); n = f2add(c2, t); c3 = f2sub(c2, t); c2 = n;
      t = cmul(c2, wA);  n = f2add(c0, t); c2 = f2sub(c0, t); c0 = n;
      t = cmul(c3, wB);  n = f2add(c1, t); c3 = f2sub(c1, t); c1 = n;
    }
  }
};

// K1: per (b, z1) plane. x-FFT streamed from global; y-FFT from LDS columns;
// results written straight to Z(b, x, z1, y) (y-contiguous).
__global__ __launch_bounds__(1024) void k_fwd_xy(const float* __restrict__ v1,
                                                 const float* __restrict__ v2,
                                                 float2* __restrict__ Z) {
  __shared__ float2 s[V * PF];
  const int tid = threadIdx.x, lane = tid & 63, wave = tid >> 6;
  const int ll = lane & 31, half = lane >> 5;
  const int b = blockIdx.x >> 7, z1 = blockIdx.x & 127;
  WF4<false> F;
  F.init(lane);
  const size_t ibase = (size_t)b * V3 + (size_t)z1 * V2;
#pragma unroll 2
  for (int it = 0; it < 4; ++it) {
    const int y = it * 32 + wave * 2 + half;
    const size_t g = ibase + (size_t)y * V;
    float2 c0 = make_float2(v1[g + ll],      v2[g + ll]);
    float2 c1 = make_float2(v1[g + 32 + ll], v2[g + 32 + ll]);
    float2 c2 = make_float2(v1[g + 64 + ll], v2[g + 64 + ll]);
    float2 c3 = make_float2(v1[g + 96 + ll], v2[g + 96 + ll]);
    F.run(c0, c1, c2, c3);
    s[y * PF + ll] = c0;        s[y * PF + 32 + ll] = c1;
    s[y * PF + 64 + ll] = c2;   s[y * PF + 96 + ll] = c3;
  }
  __syncthreads();
#pragma unroll 2
  for (int it = 0; it < 4; ++it) {
    const int x = it * 32 + wave * 2 + half;
    float2 c0 = s[ll * PF + x];
    float2 c1 = s[(32 + ll) * PF + x];
    float2 c2 = s[(64 + ll) * PF + x];
    float2 c3 = s[(96 + ll) * PF + x];
    F.run(c0, c1, c2, c3);
    const size_t zb = ((size_t)(b * V + x) * V + z1) * V;
    Z[zb + ll] = c0;       Z[zb + 32 + ll] = c1;
    Z[zb + 64 + ll] = c2;  Z[zb + 96 + ll] = c3;
  }
}

// K2: per (b, x-pair, y-half). Contiguous (z,y) tiles; fwd z-FFT + combine +
// inv z-FFT in LDS.
__global__ __launch_bounds__(1024) void k_z_fused(float2* __restrict__ Z) {
  __shared__ float2 T[2 * TILE];
  const int tid = threadIdx.x, lane = tid & 63, wave = tid >> 6;
  const int ll = lane & 31, half = lane >> 5;
  const int blk = blockIdx.x;
  const int b = blk / 130, r = blk % 130, g = r >> 1, yh = r & 1;
  int xA, xB;
  if (g < 2) {                   // negrev(0)=0, negrev(1)=1: self-paired
    xA = xB = g;
  } else {
    int cnt = g - 2, j;
    for (j = 0; j < 128; ++j) {
      if (j < negrev(j)) {
        if (cnt == 0) break;
        --cnt;
      }
    }
    xA = j; xB = negrev(j);
  }
  const bool self = (xA == xB);
  WF4<false> Ff;  Ff.init(lane);
  WF4<true>  Fi;  Fi.init(lane);
  const size_t baseA = (size_t)(b * V + xA) * V2 + yh * 64;
  const size_t baseB = (size_t)(b * V + xB) * V2 + yh * 64;

  for (int p = tid; p < 8192; p += 1024) {
    const int z = p >> 6, y = p & 63;
    T[z * PH + y] = Z[baseA + (size_t)z * V + y];
  }
  if (!self) {
    for (int p = tid; p < 8192; p += 1024) {
      const int z = p >> 6, y = p & 63;
      T[TILE + z * PH + y] = Z[baseB + (size_t)z * V + y];
    }
  }
  __syncthreads();

  const int ncol = self ? 64 : 128;
  for (int cc = wave * 2 + half; cc < ncol; cc += 32) {   // forward z-FFT
    const int tb = (cc >> 6) * TILE, y = cc & 63;
    float2 c0 = T[tb + ll * PH + y];
    float2 c1 = T[tb + (32 + ll) * PH + y];
    float2 c2 = T[tb + (64 + ll) * PH + y];
    float2 c3 = T[tb + (96 + ll) * PH + y];
    Ff.run(c0, c1, c2, c3);
    T[tb + ll * PH + y] = c0;        T[tb + (32 + ll) * PH + y] = c1;
    T[tb + (64 + ll) * PH + y] = c2; T[tb + (96 + ll) * PH + y] = c3;
  }
  __syncthreads();

  if (!self) {
    for (int p = tid; p < 8192; p += 1024) {
      const int z = p >> 6, y = p & 63;
      const int zm = negrev(z), ym = negrev(yh * 64 + y) & 63;
      const float2 a  = T[z * PH + y];
      const float2 bb = T[TILE + zm * PH + ym];
      const float f1r = 0.5f * (a.x + bb.x), f1i = 0.5f * (a.y - bb.y);
      const float f2r = 0.5f * (a.y + bb.y), f2i = 0.5f * (bb.x - a.x);
      const float gr = f1r * f2r + f1i * f2i;
      const float gi = f1i * f2r - f1r * f2i;
      T[z * PH + y] = make_float2(gr, gi);
      T[TILE + zm * PH + ym] = make_float2(gr, -gi);
    }
  } else {
    for (int p = tid; p < 8192; p += 1024) {
      const int z = p >> 6, y = p & 63;
      const int zm = negrev(z), ym = negrev(yh * 64 + y) & 63;
      const int pm = zm * 64 + ym;
      if (pm < p) continue;
      const float2 a  = T[z * PH + y];
      const float2 bb = T[zm * PH + ym];
      const float f1r = 0.5f * (a.x + bb.x), f1i = 0.5f * (a.y - bb.y);
      const float f2r = 0.5f * (a.y + bb.y), f2i = 0.5f * (bb.x - a.x);
      const float gr = f1r * f2r + f1i * f2i;
      const float gi = f1i * f2r - f1r * f2i;
      T[z * PH + y] = make_float2(gr, gi);
      if (pm != p) T[zm * PH + ym] = make_float2(gr, -gi);
    }
  }
  __syncthreads();

  for (int cc = wave * 2 + half; cc < ncol; cc += 32) {   // inverse z-FFT
    const int tb = (cc >> 6) * TILE, y = cc & 63;
    float2 c0 = T[tb + ll * PH + y];
    float2 c1 = T[tb + (32 + ll) * PH + y];
    float2 c2 = T[tb + (64 + ll) * PH + y];
    float2 c3 = T[tb + (96 + ll) * PH + y];
    Fi.run(c0, c1, c2, c3);
    T[tb + ll * PH + y] = c0;        T[tb + (32 + ll) * PH + y] = c1;
    T[tb + (64 + ll) * PH + y] = c2; T[tb + (96 + ll) * PH + y] = c3;
  }
  __syncthreads();

  for (int p = tid; p < 8192; p += 1024) {
    const int z = p >> 6, y = p & 63;
    Z[baseA + (size_t)z * V + y] = T[z * PH + y];
  }
  if (!self) {
    for (int p = tid; p < 8192; p += 1024) {
      const int z = p >> 6, y = p & 63;
      Z[baseB + (size_t)z * V + y] = T[TILE + z * PH + y];
    }
  }
}

// K3: per (b, z1) plane. Inverse y-FFT streamed from Z(b,x,z1,y-contig);
// inverse x-FFT from LDS rows; real part * 1/V^3 to out(b,z1,y,x).
__global__ __launch_bounds__(1024) void k_inv_xy(const float2* __restrict__ Z,
                                                 float* __restrict__ out) {
  __shared__ float2 s[V * PF];
  const int tid = threadIdx.x, lane = tid & 63, wave = tid >> 6;
  const int ll = lane & 31, half = lane >> 5;
  const int b = blockIdx.x >> 7, z1 = blockIdx.x & 127;
  WF4<true> F;
  F.init(lane);
#pragma unroll 2
  for (int it = 0; it < 4; ++it) {
    const int x = it * 32 + wave * 2 + half;
    const size_t zb = ((size_t)(b * V + x) * V + z1) * V;
    float2 c0 = Z[zb + ll];
    float2 c1 = Z[zb + 32 + ll];
    float2 c2 = Z[zb + 64 + ll];
    float2 c3 = Z[zb + 96 + ll];
    F.run(c0, c1, c2, c3);
    s[ll * PF + x] = c0;        s[(32 + ll) * PF + x] = c1;
    s[(64 + ll) * PF + x] = c2; s[(96 + ll) * PF + x] = c3;
  }
  __syncthreads();
  const float sc = 1.0f / 2097152.0f;  // 1/V^3
  const size_t ob = (size_t)b * V3 + (size_t)z1 * V2;
#pragma unroll 2
  for (int it = 0; it < 4; ++it) {
    const int y = it * 32 + wave * 2 + half;
    float2 c0 = s[y * PF + ll];
    float2 c1 = s[y * PF + 32 + ll];
    float2 c2 = s[y * PF + 64 + ll];
    float2 c3 = s[y * PF + 96 + ll];
    F.run(c0, c1, c2, c3);
    const size_t gg = ob + (size_t)y * V;
    out[gg + ll] = c0.x * sc;       out[gg + 32 + ll] = c1.x * sc;
    out[gg + 64 + ll] = c2.x * sc;  out[gg + 96 + ll] = c3.x * sc;
  }
}

extern "C" void kernel_launch(void* const* d_in, const int* in_sizes, int n_in,
                              void* d_out, int out_size, void* d_ws, size_t ws_size,
                              hipStream_t stream) {
  const float* v1 = (const float*)d_in[0];
  const float* v2 = (const float*)d_in[1];
  float* out = (float*)d_out;
  float2* Z  = (float2*)d_ws;  // NB*V3*8 = 128 MiB

  k_fwd_xy<<<NB * V, 1024, 0, stream>>>(v1, v2, Z);
  k_z_fused<<<NB * 130, 1024, 0, stream>>>(Z);   // 8 b x 65 x-groups x 2 y-halves
  k_inv_xy<<<NB * V, 1024, 0, stream>>>(Z, out);
}